// Round 1
// baseline (1186.821 us; speedup 1.0000x reference)
//
#include <hip/hip_runtime.h>
#include <math.h>

#define BATCH 32
#define TLEN 2048
#define DIN 512
#define HDIM 512
#define BTROWS (BATCH * TLEN)

// ---------------- GEMM: dual-output fused projection ----------------
// C_z = sigmoid((x . Wz^T + bz)/tau), C_h = x . Wh^T + bh
// tile 128x128, BK=16, 256 threads (16x16), 8x8 per-thread, dual accumulators.
#define BM 128
#define BN 128
#define BK 16
#define TM 8
#define TN 8

__device__ __forceinline__ float sigmoidf_(float v) {
    return 1.0f / (1.0f + __expf(-v));
}

__global__ __launch_bounds__(256) void gemm_dual_kernel(
    const float* __restrict__ x,    // (BT, D)
    const float* __restrict__ Wz,   // (H, D)
    const float* __restrict__ Wh,   // (H, D)
    const float* __restrict__ bz,   // (H)
    const float* __restrict__ bh,   // (H)
    const float* __restrict__ mag,  // (BT)
    const float* __restrict__ mw_p,
    const float* __restrict__ mb_p,
    const float* __restrict__ al_p,
    float* __restrict__ zbuf,       // (BT, H)  -> ws
    float* __restrict__ htbuf)      // (BT, H)  -> d_out (h_tilde, later overwritten by scan)
{
    __shared__ float As[BK][BM + 4];
    __shared__ float Zs[BK][BN + 4];
    __shared__ float Hs[BK][BN + 4];

    const int bj = blockIdx.x;           // 0..3   (col tiles adjacent -> x L2 reuse)
    const int bi = blockIdx.y;           // 0..511 (row tiles)
    const int tid = threadIdx.x;
    const int tx = tid & 15;
    const int ty = tid >> 4;
    const int row0 = bi * BM;
    const int col0 = bj * BN;

    float accZ[TM][TN];
    float accH[TM][TN];
#pragma unroll
    for (int i = 0; i < TM; ++i)
#pragma unroll
        for (int j = 0; j < TN; ++j) { accZ[i][j] = 0.f; accH[i][j] = 0.f; }

    // staging: each thread loads 2 float4 per tile (128 rows x 16 k / 256 thr)
    const int srow = tid >> 1;           // 0..127
    const int skc  = (tid & 1) * 8;      // 0 or 8
    const float* xg  = x  + (size_t)(row0 + srow) * DIN + skc;
    const float* wzg = Wz + (size_t)(col0 + srow) * DIN + skc;
    const float* whg = Wh + (size_t)(col0 + srow) * DIN + skc;

    for (int k0 = 0; k0 < DIN; k0 += BK) {
        const float4 a0 = *(const float4*)(xg  + k0);
        const float4 a1 = *(const float4*)(xg  + k0 + 4);
        const float4 z0 = *(const float4*)(wzg + k0);
        const float4 z1 = *(const float4*)(wzg + k0 + 4);
        const float4 h0 = *(const float4*)(whg + k0);
        const float4 h1 = *(const float4*)(whg + k0 + 4);

        __syncthreads();   // previous iteration's reads done before overwrite

        As[skc + 0][srow] = a0.x; As[skc + 1][srow] = a0.y;
        As[skc + 2][srow] = a0.z; As[skc + 3][srow] = a0.w;
        As[skc + 4][srow] = a1.x; As[skc + 5][srow] = a1.y;
        As[skc + 6][srow] = a1.z; As[skc + 7][srow] = a1.w;

        Zs[skc + 0][srow] = z0.x; Zs[skc + 1][srow] = z0.y;
        Zs[skc + 2][srow] = z0.z; Zs[skc + 3][srow] = z0.w;
        Zs[skc + 4][srow] = z1.x; Zs[skc + 5][srow] = z1.y;
        Zs[skc + 6][srow] = z1.z; Zs[skc + 7][srow] = z1.w;

        Hs[skc + 0][srow] = h0.x; Hs[skc + 1][srow] = h0.y;
        Hs[skc + 2][srow] = h0.z; Hs[skc + 3][srow] = h0.w;
        Hs[skc + 4][srow] = h1.x; Hs[skc + 5][srow] = h1.y;
        Hs[skc + 6][srow] = h1.z; Hs[skc + 7][srow] = h1.w;

        __syncthreads();

#pragma unroll
        for (int kk = 0; kk < BK; ++kk) {
            const float4 av0 = *(const float4*)&As[kk][ty * TM];
            const float4 av1 = *(const float4*)&As[kk][ty * TM + 4];
            const float4 zv0 = *(const float4*)&Zs[kk][tx * TN];
            const float4 zv1 = *(const float4*)&Zs[kk][tx * TN + 4];
            const float4 hv0 = *(const float4*)&Hs[kk][tx * TN];
            const float4 hv1 = *(const float4*)&Hs[kk][tx * TN + 4];
            const float a[TM]  = {av0.x, av0.y, av0.z, av0.w, av1.x, av1.y, av1.z, av1.w};
            const float zw[TN] = {zv0.x, zv0.y, zv0.z, zv0.w, zv1.x, zv1.y, zv1.z, zv1.w};
            const float hw[TN] = {hv0.x, hv0.y, hv0.z, hv0.w, hv1.x, hv1.y, hv1.z, hv1.w};
#pragma unroll
            for (int i = 0; i < TM; ++i) {
#pragma unroll
                for (int j = 0; j < TN; ++j) {
                    accZ[i][j] = fmaf(a[i], zw[j], accZ[i][j]);
                    accH[i][j] = fmaf(a[i], hw[j], accH[i][j]);
                }
            }
        }
    }

    // -------- epilogue: bias, tau, sigmoid; write z -> zbuf, h_tilde -> htbuf
    const float mwv = *mw_p;
    const float mbv = *mb_p;
    const float alv = *al_p;
    // softplus(alpha), numerically safe
    const float asp = fmaxf(alv, 0.f) + log1pf(__expf(-fabsf(alv)));

    float bzv[TN], bhv[TN];
#pragma unroll
    for (int j = 0; j < TN; ++j) {
        bzv[j] = bz[col0 + tx * TN + j];
        bhv[j] = bh[col0 + tx * TN + j];
    }

#pragma unroll
    for (int i = 0; i < TM; ++i) {
        const int r = row0 + ty * TM + i;
        const float tau  = 1.0f + asp * sigmoidf_(mwv * mag[r] + mbv);
        const float itau = 1.0f / tau;
        float zo[TN], ho[TN];
#pragma unroll
        for (int j = 0; j < TN; ++j) {
            zo[j] = sigmoidf_((accZ[i][j] + bzv[j]) * itau);
            ho[j] = accH[i][j] + bhv[j];
        }
        float* zp = zbuf  + (size_t)r * HDIM + col0 + tx * TN;
        float* hp = htbuf + (size_t)r * HDIM + col0 + tx * TN;
        *(float4*)(zp)     = make_float4(zo[0], zo[1], zo[2], zo[3]);
        *(float4*)(zp + 4) = make_float4(zo[4], zo[5], zo[6], zo[7]);
        *(float4*)(hp)     = make_float4(ho[0], ho[1], ho[2], ho[3]);
        *(float4*)(hp + 4) = make_float4(ho[4], ho[5], ho[6], ho[7]);
    }
}

// ---------------- sequential scan: h_t = h + z*(ht - h) ----------------
// one thread per (b,h); 16-deep double-buffered register prefetch.
__global__ __launch_bounds__(64) void scan_kernel(
    const float* __restrict__ zb,   // (B,T,H)
    float* __restrict__ hio)        // (B,T,H): h_tilde in, h out (in-place)
{
    const int u = blockIdx.x * 64 + threadIdx.x;   // 0..16383
    const int b = u >> 9;
    const int h = u & 511;
    const size_t base = (size_t)b * (size_t)(TLEN * HDIM) + h;
    const float* zp = zb + base;
    float* hp = hio + base;

    float hprev = 0.f;
    float zA[16], hA[16], zB[16], hB[16];

#pragma unroll
    for (int k = 0; k < 16; ++k) {
        zA[k] = zp[(size_t)k * HDIM];
        hA[k] = hp[(size_t)k * HDIM];
    }

    for (int t0 = 0; t0 < TLEN; t0 += 32) {
        // prefetch B group (t0+16 .. t0+31)
#pragma unroll
        for (int k = 0; k < 16; ++k) {
            zB[k] = zp[(size_t)(t0 + 16 + k) * HDIM];
            hB[k] = hp[(size_t)(t0 + 16 + k) * HDIM];
        }
        // compute + store A group
#pragma unroll
        for (int k = 0; k < 16; ++k) {
            hprev = fmaf(zA[k], hA[k] - hprev, hprev);
            hp[(size_t)(t0 + k) * HDIM] = hprev;
        }
        // prefetch A group (t0+32 .. t0+47)
        if (t0 + 32 < TLEN) {
#pragma unroll
            for (int k = 0; k < 16; ++k) {
                zA[k] = zp[(size_t)(t0 + 32 + k) * HDIM];
                hA[k] = hp[(size_t)(t0 + 32 + k) * HDIM];
            }
        }
        // compute + store B group
#pragma unroll
        for (int k = 0; k < 16; ++k) {
            hprev = fmaf(zB[k], hB[k] - hprev, hprev);
            hp[(size_t)(t0 + 16 + k) * HDIM] = hprev;
        }
    }
}

extern "C" void kernel_launch(void* const* d_in, const int* in_sizes, int n_in,
                              void* d_out, int out_size, void* d_ws, size_t ws_size,
                              hipStream_t stream) {
    const float* x   = (const float*)d_in[0];
    const float* mag = (const float*)d_in[1];
    const float* Wz  = (const float*)d_in[2];
    const float* bz  = (const float*)d_in[3];
    const float* Wh  = (const float*)d_in[4];
    const float* bh  = (const float*)d_in[5];
    const float* mw  = (const float*)d_in[6];
    const float* mb  = (const float*)d_in[7];
    const float* al  = (const float*)d_in[8];

    float* out  = (float*)d_out;
    float* zbuf = (float*)d_ws;   // needs BT*H*4 = 134 MB

    // grid: col tiles fastest so 4 blocks sharing an x row-panel are adjacent (L2 reuse of x)
    dim3 grid(HDIM / BN, BTROWS / BM);   // (4, 512)
    gemm_dual_kernel<<<grid, 256, 0, stream>>>(x, Wz, Wh, bz, bh, mag, mw, mb, al, zbuf, out);

    scan_kernel<<<BATCH * HDIM / 64, 64, 0, stream>>>(zbuf, out);
}

// Round 2
// 615.070 us; speedup vs baseline: 1.9296x; 1.9296x over previous
//
#include <hip/hip_runtime.h>
#include <math.h>

#define BATCH 32
#define TLEN 2048
#define DIN 512
#define HDIM 512
#define BTROWS (BATCH * TLEN)

typedef __attribute__((ext_vector_type(8))) short short8;
typedef __attribute__((ext_vector_type(4))) float f32x4;

__device__ __forceinline__ float sigmoidf_(float v) {
    return 1.0f / (1.0f + __expf(-v));
}

__device__ __forceinline__ unsigned short bf16_rne(float f) {
    unsigned int u = __float_as_uint(f);
    u += 0x7FFFu + ((u >> 16) & 1u);
    return (unsigned short)(u >> 16);
}

// ============================================================================
// Conversion: fp32 -> (hi, lo) bf16 planes in MFMA-fragment-order tiled layout.
// Tile = 128 rows x 32 k. Within tile: subtile s = row/16 (8), j = k/8 (4),
// r = row%16, e = k%8.  elem offset = s*512 + j*128 + r*8 + e  (512 elems/subtile
// = 1024B; lane l of a wave reads shorts [l*8..l*8+7] of a subtile => ds_read_b128
// at base + l*16, fully linear, zero bank conflicts).
// Global image per (tile) is the 4096-elem (8KB) LDS image, tiles sequential.
// ============================================================================
__device__ __forceinline__ void conv_body(const float* src, int t, size_t tile,
                                          short* Hs, short* Ls,
                                          short* __restrict__ dhi, short* __restrict__ dlo) {
    const int row = t >> 1, half = t & 1;
    float v[16];
#pragma unroll
    for (int i = 0; i < 4; ++i)
        *(float4*)&v[i * 4] = *(const float4*)(src + i * 4);
    const int s = row >> 4, r = row & 15;
#pragma unroll
    for (int jj = 0; jj < 2; ++jj) {
        short8 hv, lv;
#pragma unroll
        for (int e = 0; e < 8; ++e) {
            const float f = v[jj * 8 + e];
            const unsigned short h = bf16_rne(f);
            const float hf = __uint_as_float(((unsigned int)h) << 16);
            hv[e] = (short)h;
            lv[e] = (short)bf16_rne(f - hf);
        }
        const int idx = s * 512 + (half * 2 + jj) * 128 + r * 8;
        *(short8*)&Hs[idx] = hv;
        *(short8*)&Ls[idx] = lv;
    }
    __syncthreads();
    const size_t ob = tile * 4096 + (size_t)t * 16;
    *(short8*)(dhi + ob)     = *(short8*)&Hs[t * 16];
    *(short8*)(dhi + ob + 8) = *(short8*)&Hs[t * 16 + 8];
    *(short8*)(dlo + ob)     = *(short8*)&Ls[t * 16];
    *(short8*)(dlo + ob + 8) = *(short8*)&Ls[t * 16 + 8];
}

__global__ __launch_bounds__(256) void convert_x_kernel(const float* __restrict__ x,
                                                        short* __restrict__ xhi,
                                                        short* __restrict__ xlo) {
    __shared__ short Hs[4096], Ls[4096];
    const int tile = blockIdx.x;                 // rt*16 + kt
    const int rt = tile >> 4, kt = tile & 15;
    const int t = threadIdx.x;
    const int row = t >> 1, half = t & 1;
    const float* src = x + (size_t)(rt * 128 + row) * DIN + kt * 32 + half * 16;
    conv_body(src, t, (size_t)tile, Hs, Ls, xhi, xlo);
}

__global__ __launch_bounds__(256) void convert_w_kernel(const float* __restrict__ Wz,
                                                        const float* __restrict__ Wh,
                                                        short* __restrict__ whi,
                                                        short* __restrict__ wlo) {
    __shared__ short Hs[4096], Ls[4096];
    const int tile = blockIdx.x;                 // ct*16 + kt, ct in 0..7 (concat [Wz;Wh])
    const int ct = tile >> 4, kt = tile & 15;
    const int t = threadIdx.x;
    const int row = t >> 1, half = t & 1;
    const int wrow = ct * 128 + row;
    const float* base = (wrow < HDIM) ? (Wz + (size_t)wrow * DIN)
                                      : (Wh + (size_t)(wrow - HDIM) * DIN);
    const float* src = base + kt * 32 + half * 16;
    conv_body(src, t, (size_t)tile, Hs, Ls, whi, wlo);
}

// ============================================================================
// MFMA GEMM: C' = x . [Wz;Wh]^T, split-bf16 3-product (hi*hi + lo*hi + hi*lo).
// 128x128 tile, BK=32, 4 waves in 2x2, each wave 64x64 via 4x4 16x16x32 frags.
// Staging: global_load_lds_dwordx4, linear LDS image. Fused epilogue.
// ============================================================================
#define GLOAD16(g, l) __builtin_amdgcn_global_load_lds(                         \
    (const __attribute__((address_space(1))) unsigned int*)(g),                 \
    (__attribute__((address_space(3))) unsigned int*)(l), 16, 0, 0)

__global__ __launch_bounds__(256) void gemm_mfma_kernel(
    const short* __restrict__ xhi, const short* __restrict__ xlo,
    const short* __restrict__ whi, const short* __restrict__ wlo,
    const float* __restrict__ bz, const float* __restrict__ bh,
    const float* __restrict__ mag,
    const float* __restrict__ mw_p, const float* __restrict__ mb_p,
    const float* __restrict__ al_p,
    float* __restrict__ zbuf, float* __restrict__ out)
{
    __shared__ short Ah[4096], Al[4096], Bh[4096], Bl[4096];

    // bijective XCD swizzle: each XCD owns a contiguous row-tile range (4096%8==0)
    const int orig = blockIdx.x;
    const int xcd = orig & 7, idx = orig >> 3;
    const int wg = xcd * 512 + idx;
    const int bj = wg & 7;           // col tile in concat space (0..3 -> z, 4..7 -> h)
    const int bi = wg >> 3;          // row tile 0..511

    const int tid = threadIdx.x;
    const int w = tid >> 6, l = tid & 63;
    const int wr = w >> 1, wc = w & 1;

    f32x4 acc[4][4];
#pragma unroll
    for (int i = 0; i < 4; ++i)
#pragma unroll
        for (int j = 0; j < 4; ++j) acc[i][j] = (f32x4)0.f;

    const size_t ab = (size_t)bi * (16 * 4096);
    const size_t bb = (size_t)bj * (16 * 4096);
    const int c0 = tid, c1 = tid + 256;          // 16B-chunk ids within 8KB tile
    const int lb0 = (w * 64) * 8;                // wave-uniform LDS short base, i=0
    const int lb1 = (256 + w * 64) * 8;          // i=1

    for (int kt = 0; kt < 16; ++kt) {
        const size_t ta = ab + (size_t)kt * 4096;
        const size_t tb = bb + (size_t)kt * 4096;
        GLOAD16(xhi + ta + c0 * 8, &Ah[lb0]);
        GLOAD16(xhi + ta + c1 * 8, &Ah[lb1]);
        GLOAD16(xlo + ta + c0 * 8, &Al[lb0]);
        GLOAD16(xlo + ta + c1 * 8, &Al[lb1]);
        GLOAD16(whi + tb + c0 * 8, &Bh[lb0]);
        GLOAD16(whi + tb + c1 * 8, &Bh[lb1]);
        GLOAD16(wlo + tb + c0 * 8, &Bl[lb0]);
        GLOAD16(wlo + tb + c1 * 8, &Bl[lb1]);
        __syncthreads();   // compiler drains vmcnt before s_barrier -> LDS ready

        short8 av[4], aw[4], bv[4], bw[4];
#pragma unroll
        for (int i = 0; i < 4; ++i) {
            av[i] = *(const short8*)&Ah[(wr * 4 + i) * 512 + l * 8];
            aw[i] = *(const short8*)&Al[(wr * 4 + i) * 512 + l * 8];
            bv[i] = *(const short8*)&Bh[(wc * 4 + i) * 512 + l * 8];
            bw[i] = *(const short8*)&Bl[(wc * 4 + i) * 512 + l * 8];
        }
#pragma unroll
        for (int i = 0; i < 4; ++i)
#pragma unroll
            for (int j = 0; j < 4; ++j) {
                acc[i][j] = __builtin_amdgcn_mfma_f32_16x16x32_bf16(av[i], bv[j], acc[i][j], 0, 0, 0);
                acc[i][j] = __builtin_amdgcn_mfma_f32_16x16x32_bf16(aw[i], bv[j], acc[i][j], 0, 0, 0);
                acc[i][j] = __builtin_amdgcn_mfma_f32_16x16x32_bf16(av[i], bw[j], acc[i][j], 0, 0, 0);
            }
        __syncthreads();   // protect LDS from next stage
    }

    // ---------------- fused epilogue ----------------
    const float mwv = *mw_p, mbv = *mb_p, alv = *al_p;
    const float asp = fmaxf(alv, 0.f) + log1pf(__expf(-fabsf(alv)));   // softplus(alpha)
    const int colbase = bj * 128 + wc * 64 + (l & 15);
    const int rowbase = bi * 128 + wr * 64 + ((l >> 4) << 2);

    if (bj < 4) {   // z block: sigmoid((acc+bz)/tau)
        float itau[4][4];
#pragma unroll
        for (int i = 0; i < 4; ++i)
#pragma unroll
            for (int q = 0; q < 4; ++q) {
                const int row = rowbase + i * 16 + q;
                const float tau = 1.0f + asp * sigmoidf_(mwv * mag[row] + mbv);
                itau[i][q] = 1.0f / tau;
            }
#pragma unroll
        for (int j = 0; j < 4; ++j) {
            const int col = colbase + j * 16;
            const float bzv = bz[col];
#pragma unroll
            for (int i = 0; i < 4; ++i)
#pragma unroll
                for (int q = 0; q < 4; ++q) {
                    const int row = rowbase + i * 16 + q;
                    zbuf[(size_t)row * HDIM + col] = sigmoidf_((acc[i][j][q] + bzv) * itau[i][q]);
                }
        }
    } else {        // h_tilde block: acc + bh
#pragma unroll
        for (int j = 0; j < 4; ++j) {
            const int col = colbase + j * 16 - HDIM;
            const float bhv = bh[col];
#pragma unroll
            for (int i = 0; i < 4; ++i)
#pragma unroll
                for (int q = 0; q < 4; ++q) {
                    const int row = rowbase + i * 16 + q;
                    out[(size_t)row * HDIM + col] = acc[i][j][q] + bhv;
                }
        }
    }
}

// ============================================================================
// Fallback fp32 GEMM (round-1, used only if ws_size too small for bf16 planes)
// ============================================================================
#define BM 128
#define BN 128
#define BK 16
#define TM 8
#define TN 8

__global__ __launch_bounds__(256) void gemm_dual_kernel(
    const float* __restrict__ x, const float* __restrict__ Wz, const float* __restrict__ Wh,
    const float* __restrict__ bz, const float* __restrict__ bh, const float* __restrict__ mag,
    const float* __restrict__ mw_p, const float* __restrict__ mb_p, const float* __restrict__ al_p,
    float* __restrict__ zbuf, float* __restrict__ htbuf)
{
    __shared__ float As[BK][BM + 4];
    __shared__ float Zs[BK][BN + 4];
    __shared__ float Hs[BK][BN + 4];

    const int bj = blockIdx.x, bi = blockIdx.y;
    const int tid = threadIdx.x;
    const int tx = tid & 15, ty = tid >> 4;
    const int row0 = bi * BM, col0 = bj * BN;

    float accZ[TM][TN], accH[TM][TN];
#pragma unroll
    for (int i = 0; i < TM; ++i)
#pragma unroll
        for (int j = 0; j < TN; ++j) { accZ[i][j] = 0.f; accH[i][j] = 0.f; }

    const int srow = tid >> 1;
    const int skc = (tid & 1) * 8;
    const float* xg = x + (size_t)(row0 + srow) * DIN + skc;
    const float* wzg = Wz + (size_t)(col0 + srow) * DIN + skc;
    const float* whg = Wh + (size_t)(col0 + srow) * DIN + skc;

    for (int k0 = 0; k0 < DIN; k0 += BK) {
        const float4 a0 = *(const float4*)(xg + k0);
        const float4 a1 = *(const float4*)(xg + k0 + 4);
        const float4 z0 = *(const float4*)(wzg + k0);
        const float4 z1 = *(const float4*)(wzg + k0 + 4);
        const float4 h0 = *(const float4*)(whg + k0);
        const float4 h1 = *(const float4*)(whg + k0 + 4);
        __syncthreads();
        As[skc + 0][srow] = a0.x; As[skc + 1][srow] = a0.y; As[skc + 2][srow] = a0.z; As[skc + 3][srow] = a0.w;
        As[skc + 4][srow] = a1.x; As[skc + 5][srow] = a1.y; As[skc + 6][srow] = a1.z; As[skc + 7][srow] = a1.w;
        Zs[skc + 0][srow] = z0.x; Zs[skc + 1][srow] = z0.y; Zs[skc + 2][srow] = z0.z; Zs[skc + 3][srow] = z0.w;
        Zs[skc + 4][srow] = z1.x; Zs[skc + 5][srow] = z1.y; Zs[skc + 6][srow] = z1.z; Zs[skc + 7][srow] = z1.w;
        Hs[skc + 0][srow] = h0.x; Hs[skc + 1][srow] = h0.y; Hs[skc + 2][srow] = h0.z; Hs[skc + 3][srow] = h0.w;
        Hs[skc + 4][srow] = h1.x; Hs[skc + 5][srow] = h1.y; Hs[skc + 6][srow] = h1.z; Hs[skc + 7][srow] = h1.w;
        __syncthreads();
#pragma unroll
        for (int kk = 0; kk < BK; ++kk) {
            const float4 av0 = *(const float4*)&As[kk][ty * TM];
            const float4 av1 = *(const float4*)&As[kk][ty * TM + 4];
            const float4 zv0 = *(const float4*)&Zs[kk][tx * TN];
            const float4 zv1 = *(const float4*)&Zs[kk][tx * TN + 4];
            const float4 hv0 = *(const float4*)&Hs[kk][tx * TN];
            const float4 hv1 = *(const float4*)&Hs[kk][tx * TN + 4];
            const float a[TM] = {av0.x, av0.y, av0.z, av0.w, av1.x, av1.y, av1.z, av1.w};
            const float zw[TN] = {zv0.x, zv0.y, zv0.z, zv0.w, zv1.x, zv1.y, zv1.z, zv1.w};
            const float hw[TN] = {hv0.x, hv0.y, hv0.z, hv0.w, hv1.x, hv1.y, hv1.z, hv1.w};
#pragma unroll
            for (int i = 0; i < TM; ++i)
#pragma unroll
                for (int j = 0; j < TN; ++j) {
                    accZ[i][j] = fmaf(a[i], zw[j], accZ[i][j]);
                    accH[i][j] = fmaf(a[i], hw[j], accH[i][j]);
                }
        }
    }

    const float mwv = *mw_p, mbv = *mb_p, alv = *al_p;
    const float asp = fmaxf(alv, 0.f) + log1pf(__expf(-fabsf(alv)));
    float bzv[TN], bhv[TN];
#pragma unroll
    for (int j = 0; j < TN; ++j) {
        bzv[j] = bz[col0 + tx * TN + j];
        bhv[j] = bh[col0 + tx * TN + j];
    }
#pragma unroll
    for (int i = 0; i < TM; ++i) {
        const int r = row0 + ty * TM + i;
        const float tau = 1.0f + asp * sigmoidf_(mwv * mag[r] + mbv);
        const float itau = 1.0f / tau;
        float zo[TN], ho[TN];
#pragma unroll
        for (int j = 0; j < TN; ++j) {
            zo[j] = sigmoidf_((accZ[i][j] + bzv[j]) * itau);
            ho[j] = accH[i][j] + bhv[j];
        }
        float* zp = zbuf + (size_t)r * HDIM + col0 + tx * TN;
        float* hp = htbuf + (size_t)r * HDIM + col0 + tx * TN;
        *(float4*)(zp) = make_float4(zo[0], zo[1], zo[2], zo[3]);
        *(float4*)(zp + 4) = make_float4(zo[4], zo[5], zo[6], zo[7]);
        *(float4*)(hp) = make_float4(ho[0], ho[1], ho[2], ho[3]);
        *(float4*)(hp + 4) = make_float4(ho[4], ho[5], ho[6], ho[7]);
    }
}

// ---------------- sequential scan: h_t = h + z*(ht - h) ----------------
__global__ __launch_bounds__(64) void scan_kernel(
    const float* __restrict__ zb, float* __restrict__ hio)
{
    const int u = blockIdx.x * 64 + threadIdx.x;
    const int b = u >> 9;
    const int h = u & 511;
    const size_t base = (size_t)b * (size_t)(TLEN * HDIM) + h;
    const float* zp = zb + base;
    float* hp = hio + base;

    float hprev = 0.f;
    float zA[16], hA[16], zB[16], hB[16];
#pragma unroll
    for (int k = 0; k < 16; ++k) {
        zA[k] = zp[(size_t)k * HDIM];
        hA[k] = hp[(size_t)k * HDIM];
    }
    for (int t0 = 0; t0 < TLEN; t0 += 32) {
#pragma unroll
        for (int k = 0; k < 16; ++k) {
            zB[k] = zp[(size_t)(t0 + 16 + k) * HDIM];
            hB[k] = hp[(size_t)(t0 + 16 + k) * HDIM];
        }
#pragma unroll
        for (int k = 0; k < 16; ++k) {
            hprev = fmaf(zA[k], hA[k] - hprev, hprev);
            hp[(size_t)(t0 + k) * HDIM] = hprev;
        }
        if (t0 + 32 < TLEN) {
#pragma unroll
            for (int k = 0; k < 16; ++k) {
                zA[k] = zp[(size_t)(t0 + 32 + k) * HDIM];
                hA[k] = hp[(size_t)(t0 + 32 + k) * HDIM];
            }
        }
#pragma unroll
        for (int k = 0; k < 16; ++k) {
            hprev = fmaf(zB[k], hB[k] - hprev, hprev);
            hp[(size_t)(t0 + 16 + k) * HDIM] = hprev;
        }
    }
}

extern "C" void kernel_launch(void* const* d_in, const int* in_sizes, int n_in,
                              void* d_out, int out_size, void* d_ws, size_t ws_size,
                              hipStream_t stream) {
    const float* x   = (const float*)d_in[0];
    const float* mag = (const float*)d_in[1];
    const float* Wz  = (const float*)d_in[2];
    const float* bz  = (const float*)d_in[3];
    const float* Wh  = (const float*)d_in[4];
    const float* bh  = (const float*)d_in[5];
    const float* mw  = (const float*)d_in[6];
    const float* mb  = (const float*)d_in[7];
    const float* al  = (const float*)d_in[8];

    float* out = (float*)d_out;
    char* ws = (char*)d_ws;

    const size_t Z_BYTES  = (size_t)BTROWS * HDIM * 4;   // 134217728
    const size_t XP_BYTES = (size_t)BTROWS * DIN * 2;    // 67108864 per plane
    const size_t WP_BYTES = (size_t)(2 * HDIM) * DIN * 2; // 1048576 per plane
    const size_t NEED = Z_BYTES + 2 * XP_BYTES + 2 * WP_BYTES;

    float* zbuf = (float*)ws;

    if (ws_size >= NEED) {
        short* xhi = (short*)(ws + Z_BYTES);
        short* xlo = (short*)(ws + Z_BYTES + XP_BYTES);
        short* whi = (short*)(ws + Z_BYTES + 2 * XP_BYTES);
        short* wlo = (short*)(ws + Z_BYTES + 2 * XP_BYTES + WP_BYTES);

        convert_x_kernel<<<8192, 256, 0, stream>>>(x, xhi, xlo);
        convert_w_kernel<<<128, 256, 0, stream>>>(Wz, Wh, whi, wlo);
        gemm_mfma_kernel<<<4096, 256, 0, stream>>>(xhi, xlo, whi, wlo,
                                                   bz, bh, mag, mw, mb, al, zbuf, out);
    } else {
        dim3 grid(HDIM / BN, BTROWS / BM);
        gemm_dual_kernel<<<grid, 256, 0, stream>>>(x, Wz, Wh, bz, bh, mag, mw, mb, al, zbuf, out);
    }

    scan_kernel<<<BATCH * HDIM / 64, 64, 0, stream>>>(zbuf, out);
}

// Round 4
// 598.111 us; speedup vs baseline: 1.9843x; 1.0284x over previous
//
#include <hip/hip_runtime.h>
#include <math.h>

#define BATCH 32
#define TLEN 2048
#define DIN 512
#define HDIM 512
#define BTROWS (BATCH * TLEN)

typedef __attribute__((ext_vector_type(8))) short short8;
typedef __attribute__((ext_vector_type(4))) float f32x4;

__device__ __forceinline__ float sigmoidf_(float v) {
    return 1.0f / (1.0f + __expf(-v));
}

__device__ __forceinline__ unsigned short bf16_rne(float f) {
    unsigned int u = __float_as_uint(f);
    u += 0x7FFFu + ((u >> 16) & 1u);
    return (unsigned short)(u >> 16);
}

// ============================================================================
// Conversion: fp32 -> (hi, lo) bf16 planes in MFMA-fragment-order tiled layout.
// Tile = 128 rows x 32 k. elem offset = s*512 + j*128 + r*8 + e  where
// s=row/16, r=row%16, j=k/8, e=k%8. Lane l of a wave reads shorts [l*8..l*8+7]
// of a subtile => ds_read_b128 at base + l*16, zero bank conflicts.
// No LDS staging: direct stores land in 4 x 256B contiguous segments / instr.
// ============================================================================
__device__ __forceinline__ void conv_store(const float* __restrict__ src,
                                           int t, size_t tile,
                                           short* __restrict__ dhi,
                                           short* __restrict__ dlo) {
    const int row = t >> 1, half = t & 1;
    const int s = row >> 4, r = row & 15;
    float v[16];
#pragma unroll
    for (int i = 0; i < 4; ++i)
        *(float4*)&v[i * 4] = *(const float4*)(src + i * 4);
    const size_t ob = tile * 4096;
#pragma unroll
    for (int jj = 0; jj < 2; ++jj) {
        short8 hv, lv;
#pragma unroll
        for (int e = 0; e < 8; ++e) {
            const float f = v[jj * 8 + e];
            const unsigned short h = bf16_rne(f);
            const float hf = __uint_as_float(((unsigned int)h) << 16);
            hv[e] = (short)h;
            lv[e] = (short)bf16_rne(f - hf);
        }
        const int idx = s * 512 + (half * 2 + jj) * 128 + r * 8;
        *(short8*)(dhi + ob + idx) = hv;
        *(short8*)(dlo + ob + idx) = lv;
    }
}

__global__ __launch_bounds__(256) void convert_x_kernel(const float* __restrict__ x,
                                                        short* __restrict__ xhi,
                                                        short* __restrict__ xlo) {
    const int tile = blockIdx.x;                 // rt*16 + kt
    const int rt = tile >> 4, kt = tile & 15;
    const int t = threadIdx.x;
    const int row = t >> 1, half = t & 1;
    const float* src = x + (size_t)(rt * 128 + row) * DIN + kt * 32 + half * 16;
    conv_store(src, t, (size_t)tile, xhi, xlo);
}

__global__ __launch_bounds__(256) void convert_w_kernel(const float* __restrict__ Wz,
                                                        const float* __restrict__ Wh,
                                                        short* __restrict__ whi,
                                                        short* __restrict__ wlo) {
    const int tile = blockIdx.x;                 // ct*16 + kt, ct 0..7 (concat [Wz;Wh])
    const int ct = tile >> 4, kt = tile & 15;
    const int t = threadIdx.x;
    const int row = t >> 1, half = t & 1;
    const int wrow = ct * 128 + row;
    const float* base = (wrow < HDIM) ? (Wz + (size_t)wrow * DIN)
                                      : (Wh + (size_t)(wrow - HDIM) * DIN);
    const float* src = base + kt * 32 + half * 16;
    conv_store(src, t, (size_t)tile, whi, wlo);
}

// ============================================================================
// MFMA GEMM: C' = x . [Wz;Wh]^T, split-bf16 3-product. 128x128 tile, BK=32,
// 4 waves 2x2, 4x4 16x16x32 frags/wave. Double-buffered LDS 2-phase pipeline:
// issue next tile's global_load_lds BEFORE this tile's ds_read+MFMA, so the
// vmcnt(0) drain at the barrier lands after ~500 cyc of compute.
// ============================================================================
#define GLOAD16(g, l) __builtin_amdgcn_global_load_lds(                         \
    (const __attribute__((address_space(1))) unsigned int*)(g),                 \
    (__attribute__((address_space(3))) unsigned int*)(l), 16, 0, 0)

__global__ __launch_bounds__(256) void gemm_mfma_kernel(
    const short* __restrict__ xhi, const short* __restrict__ xlo,
    const short* __restrict__ whi, const short* __restrict__ wlo,
    const float* __restrict__ bz, const float* __restrict__ bh,
    const float* __restrict__ mag,
    const float* __restrict__ mw_p, const float* __restrict__ mb_p,
    const float* __restrict__ al_p,
    float* __restrict__ zbuf, float* __restrict__ out)
{
    __shared__ short Ah[2][4096], Al[2][4096], Bh[2][4096], Bl[2][4096];

    // bijective XCD swizzle: each XCD owns a contiguous row-tile range (4096%8==0)
    const int orig = blockIdx.x;
    const int xcd = orig & 7, idx = orig >> 3;
    const int wg = xcd * 512 + idx;
    const int bj = wg & 7;           // col tile in concat space (0..3 -> z, 4..7 -> h)
    const int bi = wg >> 3;          // row tile 0..511

    const int tid = threadIdx.x;
    const int w = tid >> 6, l = tid & 63;
    const int wr = w >> 1, wc = w & 1;

    f32x4 acc[4][4];
#pragma unroll
    for (int i = 0; i < 4; ++i)
#pragma unroll
        for (int j = 0; j < 4; ++j) acc[i][j] = (f32x4)0.f;

    const size_t ab = (size_t)bi * (16 * 4096);
    const size_t bb = (size_t)bj * (16 * 4096);
    const int c0 = tid, c1 = tid + 256;          // 16B-chunk ids within 8KB tile
    const int lb0 = (w * 64) * 8;                // wave-uniform LDS short base
    const int lb1 = (256 + w * 64) * 8;

#define STAGE(buf, kt) do {                                                     \
        const size_t ta_ = ab + (size_t)(kt) * 4096;                            \
        const size_t tb_ = bb + (size_t)(kt) * 4096;                            \
        GLOAD16(xhi + ta_ + c0 * 8, &Ah[buf][lb0]);                             \
        GLOAD16(xhi + ta_ + c1 * 8, &Ah[buf][lb1]);                             \
        GLOAD16(xlo + ta_ + c0 * 8, &Al[buf][lb0]);                             \
        GLOAD16(xlo + ta_ + c1 * 8, &Al[buf][lb1]);                             \
        GLOAD16(whi + tb_ + c0 * 8, &Bh[buf][lb0]);                             \
        GLOAD16(whi + tb_ + c1 * 8, &Bh[buf][lb1]);                             \
        GLOAD16(wlo + tb_ + c0 * 8, &Bl[buf][lb0]);                             \
        GLOAD16(wlo + tb_ + c1 * 8, &Bl[buf][lb1]);                             \
    } while (0)

    STAGE(0, 0);
    __syncthreads();   // drains vmcnt(0): buf0 ready

    for (int kt = 0; kt < 16; ++kt) {
        const int cur = kt & 1;
        if (kt < 15) STAGE(cur ^ 1, kt + 1);   // next tile flies during compute

        short8 av[4], aw[4], bv[4], bw[4];
#pragma unroll
        for (int i = 0; i < 4; ++i) {
            av[i] = *(const short8*)&Ah[cur][(wr * 4 + i) * 512 + l * 8];
            aw[i] = *(const short8*)&Al[cur][(wr * 4 + i) * 512 + l * 8];
            bv[i] = *(const short8*)&Bh[cur][(wc * 4 + i) * 512 + l * 8];
            bw[i] = *(const short8*)&Bl[cur][(wc * 4 + i) * 512 + l * 8];
        }
        __builtin_amdgcn_s_setprio(1);
#pragma unroll
        for (int i = 0; i < 4; ++i)
#pragma unroll
            for (int j = 0; j < 4; ++j) {
                acc[i][j] = __builtin_amdgcn_mfma_f32_16x16x32_bf16(av[i], bv[j], acc[i][j], 0, 0, 0);
                acc[i][j] = __builtin_amdgcn_mfma_f32_16x16x32_bf16(aw[i], bv[j], acc[i][j], 0, 0, 0);
                acc[i][j] = __builtin_amdgcn_mfma_f32_16x16x32_bf16(av[i], bw[j], acc[i][j], 0, 0, 0);
            }
        __builtin_amdgcn_s_setprio(0);
        __syncthreads();   // drains this iter's loads: next buf ready; LDS safe
    }
#undef STAGE

    // ---------------- fused epilogue ----------------
    const float mwv = *mw_p, mbv = *mb_p, alv = *al_p;
    const float asp = fmaxf(alv, 0.f) + log1pf(__expf(-fabsf(alv)));   // softplus(alpha)
    const int colbase = bj * 128 + wc * 64 + (l & 15);
    const int rowbase = bi * 128 + wr * 64 + ((l >> 4) << 2);

    if (bj < 4) {   // z block: sigmoid((acc+bz)/tau)
        float itau[4][4];
#pragma unroll
        for (int i = 0; i < 4; ++i)
#pragma unroll
            for (int q = 0; q < 4; ++q) {
                const int row = rowbase + i * 16 + q;
                const float tau = 1.0f + asp * sigmoidf_(mwv * mag[row] + mbv);
                itau[i][q] = 1.0f / tau;
            }
#pragma unroll
        for (int j = 0; j < 4; ++j) {
            const int col = colbase + j * 16;
            const float bzv = bz[col];
#pragma unroll
            for (int i = 0; i < 4; ++i)
#pragma unroll
                for (int q = 0; q < 4; ++q) {
                    const int row = rowbase + i * 16 + q;
                    zbuf[(size_t)row * HDIM + col] = sigmoidf_((acc[i][j][q] + bzv) * itau[i][q]);
                }
        }
    } else {        // h_tilde block: acc + bh
#pragma unroll
        for (int j = 0; j < 4; ++j) {
            const int col = colbase + j * 16 - HDIM;
            const float bhv = bh[col];
#pragma unroll
            for (int i = 0; i < 4; ++i)
#pragma unroll
                for (int q = 0; q < 4; ++q) {
                    const int row = rowbase + i * 16 + q;
                    out[(size_t)row * HDIM + col] = acc[i][j][q] + bhv;
                }
        }
    }
}

// ============================================================================
// Fallback fp32 GEMM (used only if ws_size too small for bf16 planes)
// ============================================================================
#define BM 128
#define BN 128
#define BK 16
#define TM 8
#define TN 8

__global__ __launch_bounds__(256) void gemm_dual_kernel(
    const float* __restrict__ x, const float* __restrict__ Wz, const float* __restrict__ Wh,
    const float* __restrict__ bz, const float* __restrict__ bh, const float* __restrict__ mag,
    const float* __restrict__ mw_p, const float* __restrict__ mb_p, const float* __restrict__ al_p,
    float* __restrict__ zbuf, float* __restrict__ htbuf)
{
    __shared__ float As[BK][BM + 4];
    __shared__ float Zs[BK][BN + 4];
    __shared__ float Hs[BK][BN + 4];

    const int bj = blockIdx.x, bi = blockIdx.y;
    const int tid = threadIdx.x;
    const int tx = tid & 15, ty = tid >> 4;
    const int row0 = bi * BM, col0 = bj * BN;

    float accZ[TM][TN], accH[TM][TN];
#pragma unroll
    for (int i = 0; i < TM; ++i)
#pragma unroll
        for (int j = 0; j < TN; ++j) { accZ[i][j] = 0.f; accH[i][j] = 0.f; }

    const int srow = tid >> 1;
    const int skc = (tid & 1) * 8;
    const float* xg = x + (size_t)(row0 + srow) * DIN + skc;
    const float* wzg = Wz + (size_t)(col0 + srow) * DIN + skc;
    const float* whg = Wh + (size_t)(col0 + srow) * DIN + skc;

    for (int k0 = 0; k0 < DIN; k0 += BK) {
        const float4 a0 = *(const float4*)(xg + k0);
        const float4 a1 = *(const float4*)(xg + k0 + 4);
        const float4 z0 = *(const float4*)(wzg + k0);
        const float4 z1 = *(const float4*)(wzg + k0 + 4);
        const float4 h0 = *(const float4*)(whg + k0);
        const float4 h1 = *(const float4*)(whg + k0 + 4);
        __syncthreads();
        As[skc + 0][srow] = a0.x; As[skc + 1][srow] = a0.y; As[skc + 2][srow] = a0.z; As[skc + 3][srow] = a0.w;
        As[skc + 4][srow] = a1.x; As[skc + 5][srow] = a1.y; As[skc + 6][srow] = a1.z; As[skc + 7][srow] = a1.w;
        Zs[skc + 0][srow] = z0.x; Zs[skc + 1][srow] = z0.y; Zs[skc + 2][srow] = z0.z; Zs[skc + 3][srow] = z0.w;
        Zs[skc + 4][srow] = z1.x; Zs[skc + 5][srow] = z1.y; Zs[skc + 6][srow] = z1.z; Zs[skc + 7][srow] = z1.w;
        Hs[skc + 0][srow] = h0.x; Hs[skc + 1][srow] = h0.y; Hs[skc + 2][srow] = h0.z; Hs[skc + 3][srow] = h0.w;
        Hs[skc + 4][srow] = h1.x; Hs[skc + 5][srow] = h1.y; Hs[skc + 6][srow] = h1.z; Hs[skc + 7][srow] = h1.w;
        __syncthreads();
#pragma unroll
        for (int kk = 0; kk < BK; ++kk) {
            const float4 av0 = *(const float4*)&As[kk][ty * TM];
            const float4 av1 = *(const float4*)&As[kk][ty * TM + 4];
            const float4 zv0 = *(const float4*)&Zs[kk][tx * TN];
            const float4 zv1 = *(const float4*)&Zs[kk][tx * TN + 4];
            const float4 hv0 = *(const float4*)&Hs[kk][tx * TN];
            const float4 hv1 = *(const float4*)&Hs[kk][tx * TN + 4];
            const float a[TM] = {av0.x, av0.y, av0.z, av0.w, av1.x, av1.y, av1.z, av1.w};
            const float zw[TN] = {zv0.x, zv0.y, zv0.z, zv0.w, zv1.x, zv1.y, zv1.z, zv1.w};
            const float hw[TN] = {hv0.x, hv0.y, hv0.z, hv0.w, hv1.x, hv1.y, hv1.z, hv1.w};
#pragma unroll
            for (int i = 0; i < TM; ++i)
#pragma unroll
                for (int j = 0; j < TN; ++j) {
                    accZ[i][j] = fmaf(a[i], zw[j], accZ[i][j]);
                    accH[i][j] = fmaf(a[i], hw[j], accH[i][j]);
                }
        }
    }

    const float mwv = *mw_p, mbv = *mb_p, alv = *al_p;
    const float asp = fmaxf(alv, 0.f) + log1pf(__expf(-fabsf(alv)));
    float bzv[TN], bhv[TN];
#pragma unroll
    for (int j = 0; j < TN; ++j) {
        bzv[j] = bz[col0 + tx * TN + j];
        bhv[j] = bh[col0 + tx * TN + j];
    }
#pragma unroll
    for (int i = 0; i < TM; ++i) {
        const int r = row0 + ty * TM + i;
        const float tau = 1.0f + asp * sigmoidf_(mwv * mag[r] + mbv);
        const float itau = 1.0f / tau;
        float zo[TN], ho[TN];
#pragma unroll
        for (int j = 0; j < TN; ++j) {
            zo[j] = sigmoidf_((accZ[i][j] + bzv[j]) * itau);
            ho[j] = accH[i][j] + bhv[j];
        }
        float* zp = zbuf + (size_t)r * HDIM + col0 + tx * TN;
        float* hp = htbuf + (size_t)r * HDIM + col0 + tx * TN;
        *(float4*)(zp) = make_float4(zo[0], zo[1], zo[2], zo[3]);
        *(float4*)(zp + 4) = make_float4(zo[4], zo[5], zo[6], zo[7]);
        *(float4*)(hp) = make_float4(ho[0], ho[1], ho[2], ho[3]);
        *(float4*)(hp + 4) = make_float4(ho[4], ho[5], ho[6], ho[7]);
    }
}

// ---------------- sequential scan: h_t = h + z*(ht - h) ----------------
// 1 thread per (b,h); 32-deep double-buffered register prefetch (4 MB in
// flight chip-wide > 2.4 MB BDP). In-place h over h_tilde is safe: every
// same-address read->write pair is dataflow-ordered.
__global__ __launch_bounds__(64) void scan_kernel(
    const float* __restrict__ zb, float* __restrict__ hio)
{
    const int u = blockIdx.x * 64 + threadIdx.x;
    const size_t base = ((size_t)(u >> 9) * (size_t)(TLEN * HDIM)) + (u & 511);
    const float* zp = zb + base;
    float* hp = hio + base;

    float hprev = 0.f;
    float zA[32], hA[32], zB[32], hB[32];
#pragma unroll
    for (int k = 0; k < 32; ++k) {
        zA[k] = zp[(size_t)k * HDIM];
        hA[k] = hp[(size_t)k * HDIM];
    }
    for (int t0 = 0; t0 < TLEN; t0 += 64) {
#pragma unroll
        for (int k = 0; k < 32; ++k) {
            zB[k] = zp[(size_t)(t0 + 32 + k) * HDIM];
            hB[k] = hp[(size_t)(t0 + 32 + k) * HDIM];
        }
#pragma unroll
        for (int k = 0; k < 32; ++k) {
            hprev = fmaf(zA[k], hA[k] - hprev, hprev);
            hp[(size_t)(t0 + k) * HDIM] = hprev;
        }
        if (t0 + 64 < TLEN) {
#pragma unroll
            for (int k = 0; k < 32; ++k) {
                zA[k] = zp[(size_t)(t0 + 64 + k) * HDIM];
                hA[k] = hp[(size_t)(t0 + 64 + k) * HDIM];
            }
        }
#pragma unroll
        for (int k = 0; k < 32; ++k) {
            hprev = fmaf(zB[k], hB[k] - hprev, hprev);
            hp[(size_t)(t0 + 32 + k) * HDIM] = hprev;
        }
    }
}

extern "C" void kernel_launch(void* const* d_in, const int* in_sizes, int n_in,
                              void* d_out, int out_size, void* d_ws, size_t ws_size,
                              hipStream_t stream) {
    const float* x   = (const float*)d_in[0];
    const float* mag = (const float*)d_in[1];
    const float* Wz  = (const float*)d_in[2];
    const float* bz  = (const float*)d_in[3];
    const float* Wh  = (const float*)d_in[4];
    const float* bh  = (const float*)d_in[5];
    const float* mw  = (const float*)d_in[6];
    const float* mb  = (const float*)d_in[7];
    const float* al  = (const float*)d_in[8];

    float* out = (float*)d_out;
    char* ws = (char*)d_ws;

    const size_t Z_BYTES  = (size_t)BTROWS * HDIM * 4;    // 134217728
    const size_t XP_BYTES = (size_t)BTROWS * DIN * 2;     // 67108864 per plane
    const size_t WP_BYTES = (size_t)(2 * HDIM) * DIN * 2; // 1048576 per plane
    const size_t NEED = Z_BYTES + 2 * XP_BYTES + 2 * WP_BYTES;

    float* zbuf = (float*)ws;

    if (ws_size >= NEED) {
        short* xhi = (short*)(ws + Z_BYTES);
        short* xlo = (short*)(ws + Z_BYTES + XP_BYTES);
        short* whi = (short*)(ws + Z_BYTES + 2 * XP_BYTES);
        short* wlo = (short*)(ws + Z_BYTES + 2 * XP_BYTES + WP_BYTES);

        convert_x_kernel<<<8192, 256, 0, stream>>>(x, xhi, xlo);
        convert_w_kernel<<<128, 256, 0, stream>>>(Wz, Wh, whi, wlo);
        gemm_mfma_kernel<<<4096, 256, 0, stream>>>(xhi, xlo, whi, wlo,
                                                   bz, bh, mag, mw, mb, al, zbuf, out);
    } else {
        dim3 grid(HDIM / BN, BTROWS / BM);
        gemm_dual_kernel<<<grid, 256, 0, stream>>>(x, Wz, Wh, bz, bh, mag, mw, mb, al, zbuf, out);
    }

    scan_kernel<<<BATCH * HDIM / 64, 64, 0, stream>>>(zbuf, out);
}